// Round 1
// 492.946 us; speedup vs baseline: 1.1331x; 1.1331x over previous
//
#include <hip/hip_runtime.h>
#include <stdint.h>

// Problem constants
#define NB    128   // batches
#define TT    64    // tokens per batch (M per batch)
#define KTOT  1024  // K for both layers
#define DHID  1024
#define DOUT  1536
#define NCAT  32

#define BK    64    // K tile (old fallback kernel)
#define TN    128   // N tile
#define PADR  72    // padded LDS row for old fallback kernel
#define NGMAX 64    // max groups: sum ceil(c_i/4) <= (128 + 3*32)/4 = 56 <= 64

typedef unsigned short u16;
typedef __attribute__((ext_vector_type(8))) short bf16x8;
typedef __attribute__((ext_vector_type(4))) float f32x4;
typedef __attribute__((ext_vector_type(4))) unsigned int uint4v;
typedef __attribute__((ext_vector_type(4))) float float4v;

__device__ __forceinline__ float bf2f(u16 u) {
    unsigned int x = ((unsigned int)u) << 16;
    return __builtin_bit_cast(float, x);
}
__device__ __forceinline__ unsigned int f2bf_u32(float f) {
    unsigned int x = __builtin_bit_cast(unsigned int, f);
    return (x + 0x7FFFu + ((x >> 16) & 1u)) >> 16;  // RNE
}
__device__ __forceinline__ u16 f2bf(float f) { return (u16)f2bf_u32(f); }

// Runtime dtype flag: 1 if float tensors are fp32, 0 if bf16.
__device__ int g_is_f32;

// Parallel dtype sniff: 64 lanes sample one word each (stride 64 words).
// bf16 data: low-half "exponent" bits (14..7) of the packed pair land in
// [120,132] ~99% for N(0,1); fp32 data: those are mantissa bits -> ~5%.
__global__ void detect_dtype(const unsigned int* __restrict__ xw) {
    const int lane = threadIdx.x;
    const unsigned int w = xw[lane * 64];
    const unsigned int e = (w >> 7) & 0xFF;
    const unsigned long long m = __ballot(e >= 120 && e <= 132);
    if (lane == 0) g_is_f32 = (__popcll(m) < 32) ? 1 : 0;
}

// async global->LDS, 16 B per lane, wave-uniform LDS base + lane*16
__device__ __forceinline__ void gload16(const void* g, void* l) {
    __builtin_amdgcn_global_load_lds(
        (const __attribute__((address_space(1))) void*)g,
        (__attribute__((address_space(3))) void*)l, 16, 0, 0);
}

// ---------------- prep: x (fp32|bf16) -> xb (bf16), 8 elems/thread ----------------
__global__ void prep_x(const void* __restrict__ x, u16* __restrict__ xb) {
    const bool f32 = (g_is_f32 != 0);
    const size_t base = ((size_t)blockIdx.x * 256 + threadIdx.x) * 8;
    if (f32) {
        const float* s = (const float*)x + base;
        float4v f0 = *(const float4v*)s;
        float4v f1 = *(const float4v*)(s + 4);
        uint4v v;
        v.x = f2bf_u32(f0.x) | (f2bf_u32(f0.y) << 16);
        v.y = f2bf_u32(f0.z) | (f2bf_u32(f0.w) << 16);
        v.z = f2bf_u32(f1.x) | (f2bf_u32(f1.y) << 16);
        v.w = f2bf_u32(f1.z) | (f2bf_u32(f1.w) << 16);
        *(uint4v*)&xb[base] = v;
    } else {
        *(uint4v*)&xb[base] = *(const uint4v*)((const u16*)x + base);
    }
}

// ---------------- build groups: counting-sort batches by category ----------------
// Emits <=NGMAX groups of up to 4 same-category batches. gcat[g] = category or -1,
// gbat[g*4+k] = batch index or -1. Every batch appears in exactly one slot.
__global__ void build_groups(const int* __restrict__ cid,
                             int* __restrict__ gcat, int* __restrict__ gbat) {
    __shared__ int cl[NB];
    __shared__ int cnt[NCAT], start[NCAT], gbase[NCAT];
    __shared__ int sorted[NB];
    const int t = threadIdx.x;
    cl[t] = cid[t];
    // init tables (overwritten later by emit phase, ordered via __syncthreads)
    if (t < NGMAX) gcat[t] = -1;
    gbat[t] = -1; gbat[NB + t] = -1;
    __syncthreads();
    if (t < NCAT) {
        int c = 0;
        for (int i = 0; i < NB; ++i) c += (cl[i] == t) ? 1 : 0;
        cnt[t] = c;
    }
    __syncthreads();
    if (t == 0) {
        int s = 0, g = 0;
        for (int c = 0; c < NCAT; ++c) {
            start[c] = s; s += cnt[c];
            gbase[c] = g; g += (cnt[c] + 3) >> 2;
        }
    }
    __syncthreads();
    {   // stable rank within category
        const int myc = cl[t];
        int r = 0;
        for (int i = 0; i < t; ++i) r += (cl[i] == myc) ? 1 : 0;
        sorted[start[myc] + r] = t;
    }
    __syncthreads();
    if (t < NCAT) {
        const int n = cnt[t], ng = (n + 3) >> 2;
        for (int j = 0; j < ng; ++j) {
            const int g = gbase[t] + j;
            gcat[g] = t;
            for (int k = 0; k < 4; ++k) {
                const int idx = j * 4 + k;
                gbat[g * 4 + k] = (idx < n) ? sorted[start[t] + idx] : -1;
            }
        }
    }
}

// ---------------- grouped GEMM ----------------
// Block = (group of <=4 same-cat batches, 128-col n-tile). 512 threads = 8 waves.
// Per K-step of 32: W slice (32k x 128n) staged ONCE, shared by up to 4 batches'
// A tiles (64x32 bf16, global_load_lds). acc[4 batches][2][2] of 16x16 frags.
// LDS chunk XOR-swizzle: chunk' = c ^ (row&3) ^ ((row>>2)&3)  (involution, both sides).
template<int NW, bool RELU, bool OUT_DYN>
__global__ __launch_bounds__(512, 4)
void gemm_grp(const u16* __restrict__ A,       // bf16 [NB][64][1024]
              const void* __restrict__ Win,    // [NCAT][1024][NW] fp32|bf16
              const void* __restrict__ BiasIn, // [NCAT][NW] fp32|bf16
              void* __restrict__ Cout,         // [NB][64][NW]
              const int* __restrict__ gcat,
              const int* __restrict__ gbat)
{
    constexpr int NT   = NW / TN;
    constexpr int NTIL = KTOT / 32;
    __shared__ __align__(16) u16 As[2][4 * TT * 32];  // 16 KB/buf: 4 slots x [64][32]
    __shared__ __align__(16) u16 Bs[2][TN * 32];      // 8 KB/buf: [128 n][32 k]

    // XCD-aware chunked swizzle (nwg % 8 == 0 for both layers)
    const int nwg = NGMAX * NT;
    int bid = blockIdx.x;
    bid = (bid & 7) * (nwg >> 3) + (bid >> 3);
    const int g   = bid / NT;
    const int nt  = bid % NT;
    const int cat = gcat[g];
    if (cat < 0) return;

    const bool f32 = (g_is_f32 != 0);
    const int t    = threadIdx.x;
    const int wave = t >> 6;
    const int lane = t & 63;
    const int l16  = lane & 15;
    const int q    = lane >> 4;
    const int wm   = wave & 1;      // m half (32 rows)
    const int wn   = wave >> 1;     // n strip (32 cols), 0..3

    const int bslot[4] = { gbat[g*4+0], gbat[g*4+1], gbat[g*4+2], gbat[g*4+3] };

    // ---- A staging map (global_load_lds, linear dest, inverse-swizzled source) ----
    // per call: 512 lanes x 16B = 2 slot-tiles of [64 rows][32 k] bf16 (4 KB each)
    const int tt   = t & 255;
    const int arow = tt >> 2;                                          // 0..63
    const int asc  = (((tt & 3) ^ ((tt >> 2) & 3) ^ ((tt >> 4) & 3)) << 3); // src k elems
    const int ah   = wave >> 2;     // slot-within-call
    const int sA0  = ah, sA1 = 2 + ah;
    const u16* aG0 = (bslot[sA0] >= 0)
        ? (A + (size_t)bslot[sA0] * (TT * KTOT) + (size_t)arow * KTOT + asc) : (const u16*)0;
    const u16* aG1 = (bslot[sA1] >= 0)
        ? (A + (size_t)bslot[sA1] * (TT * KTOT) + (size_t)arow * KTOT + asc) : (const u16*)0;

    // ---- W staging map: thread -> (n row, 8-k chunk); 8 strided coalesced loads ----
    const int bn  = t & 127;
    const int kc  = t >> 7;                                            // 0..3
    const int wch = ((kc ^ (bn & 3) ^ ((bn >> 2) & 3)) << 4);          // dest byte chunk
    const size_t wOff = (size_t)cat * ((size_t)KTOT * NW) + (size_t)(kc * 8) * NW
                        + (size_t)nt * TN + bn;
    const float* w32 = (const float*)Win + wOff;
    const u16*   w16 = (const u16*)Win + wOff;

    // fragment read: swizzled chunk byte offset (same formula for A rows and B rows)
    const int CH = ((q ^ (l16 & 3) ^ ((l16 >> 2) & 3)) << 4);

    f32x4 acc[4][2][2];
#pragma unroll
    for (int bt = 0; bt < 4; ++bt)
#pragma unroll
        for (int im = 0; im < 2; ++im)
#pragma unroll
            for (int in = 0; in < 2; ++in)
                acc[bt][im][in] = (f32x4){0.f, 0.f, 0.f, 0.f};

    unsigned int wr[8];

    auto W_ISSUE = [&](int kk) {   // issue 8 loads for tile kk (no wait)
        if (f32) {
            const float* ws = w32 + (size_t)kk * NW;
#pragma unroll
            for (int j = 0; j < 8; ++j)
                wr[j] = __builtin_bit_cast(unsigned int, ws[(size_t)j * NW]);
        } else {
            const u16* ws = w16 + (size_t)kk * NW;
#pragma unroll
            for (int j = 0; j < 8; ++j) wr[j] = ws[(size_t)j * NW];
        }
    };
    auto W_PACK = [&](int pb) {    // convert+pack, swizzled ds_write_b128
        unsigned int p[4];
#pragma unroll
        for (int i = 0; i < 4; ++i) {
            unsigned int lo, hi;
            if (f32) {
                lo = f2bf_u32(__builtin_bit_cast(float, wr[2*i]));
                hi = f2bf_u32(__builtin_bit_cast(float, wr[2*i+1]));
            } else { lo = wr[2*i]; hi = wr[2*i+1]; }
            p[i] = lo | (hi << 16);
        }
        uint4v v; v.x = p[0]; v.y = p[1]; v.z = p[2]; v.w = p[3];
        *(uint4v*)((char*)&Bs[pb][0] + bn * 64 + wch) = v;
    };
    auto A_ISSUE = [&](int pb, int kk) {  // 2 async calls, wave-uniform masked
        char* ab = (char*)&As[pb][0] + wave * 1024;
        if (aG0) gload16(aG0 + kk, ab);
        if (aG1) gload16(aG1 + kk, ab + 8192);
    };
    auto COMPUTE = [&](int pb) {
        const char* bsb = (const char*)&Bs[pb][0];
        const int nrow = wn * 32 + l16;
        bf16x8 bb0 = *(const bf16x8*)(bsb + nrow * 64 + CH);
        bf16x8 bb1 = *(const bf16x8*)(bsb + (nrow + 16) * 64 + CH);
        const char* asb = (const char*)&As[pb][0] + (wm * 32 + l16) * 64 + CH;
#pragma unroll
        for (int bt = 0; bt < 4; ++bt) {
            bf16x8 a0 = *(const bf16x8*)(asb + bt * 4096);
            bf16x8 a1 = *(const bf16x8*)(asb + bt * 4096 + 1024);
            acc[bt][0][0] = __builtin_amdgcn_mfma_f32_16x16x32_bf16(a0, bb0, acc[bt][0][0], 0, 0, 0);
            acc[bt][0][1] = __builtin_amdgcn_mfma_f32_16x16x32_bf16(a0, bb1, acc[bt][0][1], 0, 0, 0);
            acc[bt][1][0] = __builtin_amdgcn_mfma_f32_16x16x32_bf16(a1, bb0, acc[bt][1][0], 0, 0, 0);
            acc[bt][1][1] = __builtin_amdgcn_mfma_f32_16x16x32_bf16(a1, bb1, acc[bt][1][1], 0, 0, 0);
        }
    };

    // prologue: stage tile 0
    W_ISSUE(0);
    A_ISSUE(0, 0);
    W_PACK(0);
    __syncthreads();

#pragma unroll 2
    for (int tl = 0; tl < NTIL; ++tl) {
        const int cur = tl & 1;
        if (tl + 1 < NTIL) {        // issue next tile BEFORE compute (latency hides)
            W_ISSUE((tl + 1) * 32);
            A_ISSUE(cur ^ 1, (tl + 1) * 32);
        }
        COMPUTE(cur);
        if (tl + 1 < NTIL) W_PACK(cur ^ 1);   // W data has had full MFMA phase to land
        __syncthreads();
    }

    // ---- epilogue: bias (+ReLU), store. C/D: col = lane&15, row = q*4 + reg ----
    const float* bias32 = (const float*)BiasIn + (size_t)cat * NW + (size_t)nt * TN;
    const u16*   bias16 = (const u16*)BiasIn + (size_t)cat * NW + (size_t)nt * TN;
#pragma unroll
    for (int in = 0; in < 2; ++in) {
        const int ncol = wn * 32 + in * 16 + l16;
        const float bv = f32 ? bias32[ncol] : bf2f(bias16[ncol]);
#pragma unroll
        for (int bt = 0; bt < 4; ++bt) {
            const int b = bslot[bt];
            if (b < 0) continue;
            const size_t cOff = (size_t)b * (TT * NW) + (size_t)nt * TN + ncol;
#pragma unroll
            for (int im = 0; im < 2; ++im) {
#pragma unroll
                for (int r = 0; r < 4; ++r) {
                    const int m = wm * 32 + im * 16 + q * 4 + r;
                    float v = acc[bt][im][in][r] + bv;
                    if (RELU) v = fmaxf(v, 0.f);
                    if (OUT_DYN && f32) ((float*)Cout)[cOff + (size_t)m * NW] = v;
                    else                ((u16*)Cout)[cOff + (size_t)m * NW] = f2bf(v);
                }
            }
        }
    }
}

// ================= old per-batch kernel (fallback if workspace too small) =================
template<int NW, bool RELU, bool A_DYN, bool OUT_DYN>
__global__ __launch_bounds__(256, 4)
void gemm_cat(const void* __restrict__ Ain,
              const void* __restrict__ Win,
              const void* __restrict__ BiasIn,
              void* __restrict__ Cout,
              const int* __restrict__ cat_ids)
{
    constexpr int NT = NW / TN;
    __shared__ u16 As[TT * PADR];
    __shared__ u16 Bs[TN * PADR];

    const bool f32  = (g_is_f32 != 0);
    const bool aF32 = A_DYN && f32;
    const bool oF32 = OUT_DYN && f32;

    const int b   = blockIdx.x / NT;
    const int nt  = blockIdx.x % NT;
    const int cat = cat_ids[b];

    const int tid  = threadIdx.x;
    const int lane = tid & 63;
    const int l16  = lane & 15;
    const int q    = lane >> 4;
    const int wave = tid >> 6;
    const int wm   = wave & 1;
    const int wn   = wave >> 1;

    const size_t aOff = (size_t)b * (TT * KTOT);
    const u16*   Ab16 = (const u16*)Ain + aOff;
    const float* Ab32 = (const float*)Ain + aOff;
    const size_t wOff = (size_t)cat * ((size_t)KTOT * NW) + (size_t)nt * TN;
    const u16*   Wb16 = (const u16*)Win + wOff;
    const float* Wb32 = (const float*)Win + wOff;

    const int ar = tid >> 2;
    const int ac = (tid & 3) * 16;
    const int bn  = tid & 127;
    const int bk0 = tid >> 7;

    f32x4 acc[2][4];
#pragma unroll
    for (int im = 0; im < 2; ++im)
#pragma unroll
        for (int in = 0; in < 4; ++in)
            acc[im][in] = (f32x4){0.f, 0.f, 0.f, 0.f};

    for (int kk = 0; kk < KTOT; kk += BK) {
        if (!aF32) {
            const u16* src = Ab16 + ar * KTOT + kk + ac;
            uint4v v0 = *(const uint4v*)(src);
            uint4v v1 = *(const uint4v*)(src + 8);
            *(uint4v*)&As[ar * PADR + ac]     = v0;
            *(uint4v*)&As[ar * PADR + ac + 8] = v1;
        } else {
            const float* src = Ab32 + ar * KTOT + kk + ac;
            float4v f0 = *(const float4v*)(src);
            float4v f1 = *(const float4v*)(src + 4);
            float4v f2 = *(const float4v*)(src + 8);
            float4v f3 = *(const float4v*)(src + 12);
            uint4v v0, v1;
            v0.x = f2bf_u32(f0.x) | (f2bf_u32(f0.y) << 16);
            v0.y = f2bf_u32(f0.z) | (f2bf_u32(f0.w) << 16);
            v0.z = f2bf_u32(f1.x) | (f2bf_u32(f1.y) << 16);
            v0.w = f2bf_u32(f1.z) | (f2bf_u32(f1.w) << 16);
            v1.x = f2bf_u32(f2.x) | (f2bf_u32(f2.y) << 16);
            v1.y = f2bf_u32(f2.z) | (f2bf_u32(f2.w) << 16);
            v1.z = f2bf_u32(f3.x) | (f2bf_u32(f3.y) << 16);
            v1.w = f2bf_u32(f3.z) | (f2bf_u32(f3.w) << 16);
            *(uint4v*)&As[ar * PADR + ac]     = v0;
            *(uint4v*)&As[ar * PADR + ac + 8] = v1;
        }
#pragma unroll
        for (int i = 0; i < 4; ++i) {
            const int kc = bk0 + i * 2;
            unsigned int s[8];
            if (!f32) {
                const u16* src = Wb16 + (size_t)(kk + kc * 8) * NW + bn;
#pragma unroll
                for (int j = 0; j < 8; ++j) s[j] = src[(size_t)j * NW];
            } else {
                const float* src = Wb32 + (size_t)(kk + kc * 8) * NW + bn;
#pragma unroll
                for (int j = 0; j < 8; ++j) s[j] = f2bf_u32(src[(size_t)j * NW]);
            }
            uint4v v;
            v.x = s[0] | (s[1] << 16);
            v.y = s[2] | (s[3] << 16);
            v.z = s[4] | (s[5] << 16);
            v.w = s[6] | (s[7] << 16);
            *(uint4v*)&Bs[bn * PADR + kc * 8] = v;
        }
        __syncthreads();

#pragma unroll
        for (int s = 0; s < 2; ++s) {
            bf16x8 a[2], bb[4];
#pragma unroll
            for (int im = 0; im < 2; ++im)
                a[im] = *(const bf16x8*)&As[(wm * 32 + im * 16 + l16) * PADR + s * 32 + q * 8];
#pragma unroll
            for (int in = 0; in < 4; ++in)
                bb[in] = *(const bf16x8*)&Bs[(wn * 64 + in * 16 + l16) * PADR + s * 32 + q * 8];
#pragma unroll
            for (int im = 0; im < 2; ++im)
#pragma unroll
                for (int in = 0; in < 4; ++in)
                    acc[im][in] = __builtin_amdgcn_mfma_f32_16x16x32_bf16(
                        a[im], bb[in], acc[im][in], 0, 0, 0);
        }
        __syncthreads();
    }

    const u16*   bias16 = (const u16*)BiasIn + (size_t)cat * NW + nt * TN;
    const float* bias32 = (const float*)BiasIn + (size_t)cat * NW + nt * TN;
    const size_t cOff = (size_t)b * TT * NW + (size_t)nt * TN;
    u16*   C16 = (u16*)Cout + cOff;
    float* C32 = (float*)Cout + cOff;
#pragma unroll
    for (int in = 0; in < 4; ++in) {
        const int ncol = wn * 64 + in * 16 + l16;
        const float bv = f32 ? bias32[ncol] : bf2f(bias16[ncol]);
#pragma unroll
        for (int im = 0; im < 2; ++im) {
#pragma unroll
            for (int r = 0; r < 4; ++r) {
                const int m = wm * 32 + im * 16 + q * 4 + r;
                float v = acc[im][in][r] + bv;
                if (RELU) v = fmaxf(v, 0.f);
                if (oF32) C32[(size_t)m * NW + ncol] = v;
                else      C16[(size_t)m * NW + ncol] = f2bf(v);
            }
        }
    }
}

extern "C" void kernel_launch(void* const* d_in, const int* in_sizes, int n_in,
                              void* d_out, int out_size, void* d_ws, size_t ws_size,
                              hipStream_t stream) {
    const void* x   = d_in[0];   // (128,64,1024)
    const void* W1  = d_in[1];   // (32,1024,1024)
    const void* b1  = d_in[2];   // (32,1024)
    const void* W2  = d_in[3];   // (32,1024,1536)
    const void* b2  = d_in[4];   // (32,1536)
    const int*  cid = (const int*)d_in[5];   // (128,) int32

    const size_t XB_BYTES = (size_t)NB * TT * KTOT * 2;          // 16 MiB
    const size_t NEED = 2 * XB_BYTES + 4096;                     // xb + h + tables

    detect_dtype<<<1, 64, 0, stream>>>((const unsigned int*)x);

    if (ws_size >= NEED) {
        u16* xb   = (u16*)d_ws;
        u16* h    = (u16*)((char*)d_ws + XB_BYTES);
        int* gcat = (int*)((char*)d_ws + 2 * XB_BYTES);
        int* gbat = gcat + NGMAX;

        prep_x<<<4096, 256, 0, stream>>>(x, xb);
        build_groups<<<1, NB, 0, stream>>>(cid, gcat, gbat);
        gemm_grp<DHID, true,  false><<<NGMAX * (DHID / TN), 512, 0, stream>>>(
            xb, W1, b1, (void*)h, gcat, gbat);
        gemm_grp<DOUT, false, true ><<<NGMAX * (DOUT / TN), 512, 0, stream>>>(
            h, W2, b2, d_out, gcat, gbat);
    } else {
        // fallback: previous verified per-batch path (needs only h)
        u16* h = (u16*)d_ws;
        gemm_cat<DHID, true,  true,  false><<<NB * (DHID / TN), 256, 0, stream>>>(
            x, W1, b1, (void*)h, cid);
        gemm_cat<DOUT, false, false, true ><<<NB * (DOUT / TN), 256, 0, stream>>>(
            (const void*)h, W2, b2, d_out, cid);
    }
}